// Round 3
// baseline (386.843 us; speedup 1.0000x reference)
//
#include <hip/hip_runtime.h>
#include <stdint.h>

// DynamicNodeMask: reproduce jax.random.uniform(key(42),(32768,1024)) scores
// via partitionable Threefry-2x32 (JAX >= 0.4.36 default). For 32-bit draws:
//   (b1,b2) = threefry2x32(key=(0,42), counts=(n>>32, n&0xffffffff)); bits = b1 ^ b2
// Per row: k = max(floor(307.2f*factor),1); mask the k smallest scores
// (stable tie-break by index) and replace with mask_token.
// Outputs: [masked_embeds (B*E) | mask (B*E)] as float32.

#define B_ROWS 32768
#define E_COLS 1024

__device__ __forceinline__ uint32_t rotl(uint32_t x, uint32_t d) {
    return (x << d) | (x >> (32u - d));
}

// JAX threefry2x32 with key (0, 42); returns lane0 ^ lane1 (32-bit draw combine).
__device__ __forceinline__ uint32_t threefry2x32_xor(uint32_t c0, uint32_t c1) {
    const uint32_t ks0 = 0u;
    const uint32_t ks1 = 42u;
    const uint32_t ks2 = 0x1BD11BDAu ^ ks0 ^ ks1;
    uint32_t x0 = c0 + ks0;
    uint32_t x1 = c1 + ks1;
#define TF_ROUND(d) { x0 += x1; x1 = rotl(x1, d); x1 ^= x0; }
    TF_ROUND(13) TF_ROUND(15) TF_ROUND(26) TF_ROUND(6)
    x0 += ks1; x1 += ks2 + 1u;
    TF_ROUND(17) TF_ROUND(29) TF_ROUND(16) TF_ROUND(24)
    x0 += ks2; x1 += ks0 + 2u;
    TF_ROUND(13) TF_ROUND(15) TF_ROUND(26) TF_ROUND(6)
    x0 += ks0; x1 += ks1 + 3u;
    TF_ROUND(17) TF_ROUND(29) TF_ROUND(16) TF_ROUND(24)
    x0 += ks1; x1 += ks2 + 4u;
    TF_ROUND(13) TF_ROUND(15) TF_ROUND(26) TF_ROUND(6)
    x0 += ks2; x1 += ks0 + 5u;
#undef TF_ROUND
    return x0 ^ x1;   // JAX partitionable 32-bit combine: bits1 ^ bits2
}

__global__ __launch_bounds__(256) void DynamicNodeMask_kernel(
    const float* __restrict__ embeds,        // [32768,1024]
    const float* __restrict__ factors,       // [32768]
    const float* __restrict__ mask_token,    // [1024]
    float* __restrict__ out)                 // [2*32768*1024]
{
    const int t = threadIdx.x;       // 0..255
    const int r = blockIdx.x;        // row 0..32767

    __shared__ uint32_t s_hist[256];
    __shared__ uint32_t s_scan[256];
    __shared__ uint32_t s_cand_key[1024];
    __shared__ uint16_t s_cand_idx[1024];
    __shared__ uint8_t  s_flags[1024];       // 1 = masked (replaced)
    __shared__ uint32_t s_b0, s_excl, s_c;

    // ---- generate 23-bit keys (4 elements/thread, j = 4t+e) ----
    uint32_t key4[4];
#pragma unroll
    for (int e = 0; e < 4; ++e) {
        uint32_t j = (uint32_t)t * 4u + (uint32_t)e;
        uint32_t n = (uint32_t)r * 1024u + j;   // flat uint64 iota, hi=0
        key4[e] = threefry2x32_xor(0u, n) >> 9; // monotone in uniform score
    }

    const float f = factors[r];
    int k = (int)floorf(307.2f * f);          // f32 multiply, matches JAX weak-type
    if (k < 1) k = 1;

    // ---- radix-select of k-th smallest on top-8 of 23 bits ----
    s_hist[t] = 0u;
    if (t == 0) { s_b0 = 256u; s_c = 0u; }
    __syncthreads();
#pragma unroll
    for (int e = 0; e < 4; ++e)
        atomicAdd(&s_hist[key4[e] >> 15], 1u);
    __syncthreads();

    const uint32_t h = s_hist[t];
    s_scan[t] = h;
    __syncthreads();
    for (int off = 1; off < 256; off <<= 1) {
        uint32_t add = (t >= off) ? s_scan[t - off] : 0u;
        __syncthreads();
        s_scan[t] += add;
        __syncthreads();
    }
    const uint32_t incl = s_scan[t];          // inclusive prefix count
    if (incl >= (uint32_t)k) atomicMin(&s_b0, (uint32_t)t);
    __syncthreads();
    const uint32_t b0 = s_b0;                 // boundary bin
    if ((uint32_t)t == b0) s_excl = incl - h; // #elems strictly below boundary bin
    __syncthreads();
    const uint32_t excl = s_excl;
    const uint32_t kprime = (uint32_t)k - excl;  // 1 <= kprime <= |bin b0|

    // flags for non-boundary elems; gather boundary-bin candidates
    uint32_t w = 0u;
#pragma unroll
    for (int e = 0; e < 4; ++e) {
        uint32_t j = (uint32_t)t * 4u + (uint32_t)e;
        uint32_t u = key4[e];
        uint32_t bin = u >> 15;
        if (bin < b0) w |= (1u << (8 * e));
        if (bin == b0) {
            uint32_t pos = atomicAdd(&s_c, 1u);
            s_cand_key[pos] = u;
            s_cand_idx[pos] = (uint16_t)j;
        }
    }
    ((uint32_t*)&s_flags[0])[t] = w;          // packed byte flags
    __syncthreads();

    // exact stable rank among boundary-bin candidates (expected c ~ 4)
    const uint32_t c = s_c;
    for (uint32_t p = (uint32_t)t; p < c; p += 256u) {
        uint32_t up = s_cand_key[p];
        uint32_t jp = s_cand_idx[p];
        uint32_t rank = 0u;
        for (uint32_t q = 0; q < c; ++q) {
            uint32_t uq = s_cand_key[q];
            uint32_t jq = s_cand_idx[q];
            rank += (uq < up || (uq == up && jq < jp)) ? 1u : 0u;
        }
        s_flags[jp] = (rank < kprime) ? 1u : 0u;
    }
    __syncthreads();

    // ---- epilogue: vectorized select + store both outputs ----
    const float4 mtv = ((const float4*)mask_token)[t];
    const size_t half = (size_t)B_ROWS * (size_t)E_COLS;
    const size_t row = (size_t)r;
    const float4 ev = ((const float4*)(embeds + row * E_COLS))[t];
    const uint32_t wf = ((const uint32_t*)&s_flags[0])[t];
    const bool f0 = (wf & 0x000000FFu) != 0u;
    const bool f1 = (wf & 0x0000FF00u) != 0u;
    const bool f2 = (wf & 0x00FF0000u) != 0u;
    const bool f3 = (wf & 0xFF000000u) != 0u;
    float4 me, mk;
    me.x = f0 ? mtv.x : ev.x;  mk.x = f0 ? 0.0f : 1.0f;
    me.y = f1 ? mtv.y : ev.y;  mk.y = f1 ? 0.0f : 1.0f;
    me.z = f2 ? mtv.z : ev.z;  mk.z = f2 ? 0.0f : 1.0f;
    me.w = f3 ? mtv.w : ev.w;  mk.w = f3 ? 0.0f : 1.0f;
    ((float4*)(out + row * E_COLS))[t] = me;
    ((float4*)(out + half + row * E_COLS))[t] = mk;
}

extern "C" void kernel_launch(void* const* d_in, const int* in_sizes, int n_in,
                              void* d_out, int out_size, void* d_ws, size_t ws_size,
                              hipStream_t stream) {
    const float* embeds     = (const float*)d_in[0];
    const float* factors    = (const float*)d_in[1];
    const float* mask_token = (const float*)d_in[2];
    float* out = (float*)d_out;
    (void)in_sizes; (void)n_in; (void)d_ws; (void)ws_size; (void)out_size;

    dim3 grid(B_ROWS);    // one block per row
    dim3 block(256);
    DynamicNodeMask_kernel<<<grid, block, 0, stream>>>(embeds, factors, mask_token, out);
}

// Round 4
// 372.622 us; speedup vs baseline: 1.0382x; 1.0382x over previous
//
#include <hip/hip_runtime.h>
#include <stdint.h>

// DynamicNodeMask — R4: wave-per-row restructure.
// RNG (verified exact in R3): partitionable Threefry-2x32, element n bits =
//   b1 ^ b2 of threefry2x32(key=(0,42), counts=(0, n)); score order == order
//   of (bits >> 9) with stable index tie-break.
// Per row: k = max(floor(307.2f*factor),1); mask k smallest, replace with
// mask_token. Outputs: [masked_embeds | mask], float32.
// Structure: 4 waves/block, one row per wave; 16 elems/lane; wave-private
// LDS histogram + __shfl_up scan; only 3 __syncthreads per block.

#define B_ROWS 32768
#define E_COLS 1024
#define MAXC 256   // boundary-bin candidate cap (binomial mean 4, 256 is >>30 sigma)

__device__ __forceinline__ uint32_t rotl(uint32_t x, uint32_t d) {
    return (x << d) | (x >> (32u - d));
}

// JAX threefry2x32, key (0,42), counts (0, n); returns lane0 ^ lane1.
__device__ __forceinline__ uint32_t threefry_xor(uint32_t n) {
    const uint32_t ks0 = 0u;
    const uint32_t ks1 = 42u;
    const uint32_t ks2 = 0x1BD11BDAu ^ ks0 ^ ks1;
    uint32_t x0 = 0u;            // c0 (=0) + ks0 (=0)
    uint32_t x1 = n + ks1;
#define TF_ROUND(d) { x0 += x1; x1 = rotl(x1, d); x1 ^= x0; }
    TF_ROUND(13) TF_ROUND(15) TF_ROUND(26) TF_ROUND(6)
    x0 += ks1; x1 += ks2 + 1u;
    TF_ROUND(17) TF_ROUND(29) TF_ROUND(16) TF_ROUND(24)
    x0 += ks2; x1 += ks0 + 2u;
    TF_ROUND(13) TF_ROUND(15) TF_ROUND(26) TF_ROUND(6)
    x0 += ks0; x1 += ks1 + 3u;
    TF_ROUND(17) TF_ROUND(29) TF_ROUND(16) TF_ROUND(24)
    x0 += ks1; x1 += ks2 + 4u;
    TF_ROUND(13) TF_ROUND(15) TF_ROUND(26) TF_ROUND(6)
    x0 += ks2; x1 += ks0 + 5u;
#undef TF_ROUND
    return x0 ^ x1;
}

__global__ __launch_bounds__(256) void DynamicNodeMask_kernel(
    const float* __restrict__ embeds,        // [32768,1024]
    const float* __restrict__ factors,       // [32768]
    const float* __restrict__ mask_token,    // [1024]
    float* __restrict__ out)                 // [2*32768*1024]
{
    const int t    = threadIdx.x;
    const int w    = t >> 6;                 // wave 0..3
    const int lane = t & 63;
    const int r    = blockIdx.x * 4 + w;     // one row per wave

    __shared__ uint32_t s_hist[4][256];
    __shared__ uint32_t s_ckey[4][MAXC];
    __shared__ uint16_t s_cidx[4][MAXC];
    __shared__ uint32_t s_cnt[4];

    // ---- 23-bit keys: element j = chunk*256 + lane*4 + e, slot s = chunk*4+e ----
    uint32_t u[16];
#pragma unroll
    for (int chunk = 0; chunk < 4; ++chunk)
#pragma unroll
        for (int e = 0; e < 4; ++e) {
            uint32_t j = (uint32_t)chunk * 256u + (uint32_t)lane * 4u + (uint32_t)e;
            u[chunk * 4 + e] = threefry_xor((uint32_t)r * 1024u + j) >> 9;
        }

    // ---- zero wave-private hist (stride-64: conflict-free) ----
#pragma unroll
    for (int i = 0; i < 4; ++i) s_hist[w][lane + 64 * i] = 0u;
    if (lane == 0) s_cnt[w] = 0u;
    __syncthreads();   // barrier 1

    // ---- histogram on top-8 bits ----
#pragma unroll
    for (int s = 0; s < 16; ++s)
        atomicAdd(&s_hist[w][u[s] >> 15], 1u);
    __syncthreads();   // barrier 2

    // ---- wave scan over 256 bins (lane owns bins 4*lane .. 4*lane+3) ----
    uint4 hv = *(const uint4*)&s_hist[w][lane * 4];
    const uint32_t s0 = hv.x, s1 = hv.y, s2 = hv.z, s3 = hv.w;
    const uint32_t L = s0 + s1 + s2 + s3;
    uint32_t scan = L;
#pragma unroll
    for (int d = 1; d < 64; d <<= 1) {
        uint32_t v = __shfl_up(scan, (unsigned)d, 64);
        scan += (lane >= d) ? v : 0u;
    }
    const uint32_t exclLane = scan - L;

    const float f = factors[r];
    int ki = (int)floorf(307.2f * f);        // f32, matches JAX weak-type promotion
    if (ki < 1) ki = 1;
    const uint32_t k = (uint32_t)ki;

    // boundary bin: first bin whose inclusive count >= k
    const unsigned long long bal = __ballot(scan >= k);
    const int l0 = __ffsll(bal) - 1;         // first lane whose range crosses k
    const uint32_t i0 = exclLane + s0;
    const uint32_t i1 = i0 + s1;
    const uint32_t i2 = i1 + s2;
    const uint32_t i3 = i2 + s3;
    uint32_t b0loc, exloc;
    if      (i0 >= k) { b0loc = (uint32_t)lane * 4u + 0u; exloc = i0 - s0; }
    else if (i1 >= k) { b0loc = (uint32_t)lane * 4u + 1u; exloc = i1 - s1; }
    else if (i2 >= k) { b0loc = (uint32_t)lane * 4u + 2u; exloc = i2 - s2; }
    else              { b0loc = (uint32_t)lane * 4u + 3u; exloc = i3 - s3; }
    const uint32_t b0     = (uint32_t)__shfl((int)b0loc, l0, 64);
    const uint32_t excl   = (uint32_t)__shfl((int)exloc, l0, 64);
    const uint32_t kprime = k - excl;        // 1..|bin b0|

    // ---- flags in registers; gather boundary-bin candidates ----
    uint32_t m16 = 0u;
#pragma unroll
    for (int s = 0; s < 16; ++s) {
        const uint32_t bin = u[s] >> 15;
        if (bin < b0) m16 |= (1u << s);
        else if (bin == b0) {
            uint32_t pos = atomicAdd(&s_cnt[w], 1u);
            if (pos < MAXC) {
                uint32_t j = ((uint32_t)(s >> 2)) * 256u + (uint32_t)lane * 4u
                           + (uint32_t)(s & 3);
                s_ckey[w][pos] = u[s];
                s_cidx[w][pos] = (uint16_t)j;
            }
        }
    }
    __syncthreads();   // barrier 3

    // ---- exact stable rank among candidates (c ~ 4); all lanes redundantly ----
    uint32_t c = s_cnt[w];
    if (c > MAXC) c = MAXC;
    for (uint32_t p = 0; p < c; ++p) {
        const uint32_t up = s_ckey[w][p];    // broadcast reads: conflict-free
        const uint32_t jp = s_cidx[w][p];
        uint32_t rank = 0u;
        for (uint32_t q = 0; q < c; ++q) {
            const uint32_t uq = s_ckey[w][q];
            const uint32_t jq = s_cidx[w][q];
            rank += (uq < up || (uq == up && jq < jp)) ? 1u : 0u;
        }
        if (rank < kprime && (((jp >> 2) & 63u) == (uint32_t)lane))
            m16 |= 1u << ((jp >> 8) * 4u + (jp & 3u));
    }

    // ---- epilogue: float4 select + store both outputs ----
    const size_t half = (size_t)B_ROWS * (size_t)E_COLS;
    const float4* mt4 = (const float4*)mask_token;
#pragma unroll
    for (int chunk = 0; chunk < 4; ++chunk) {
        const size_t base = (size_t)r * E_COLS + (size_t)chunk * 256 + (size_t)lane * 4;
        const float4 ev  = *(const float4*)(embeds + base);
        const float4 mtv = mt4[chunk * 64 + lane];
        const bool f0 = (m16 >> (chunk * 4 + 0)) & 1u;
        const bool f1 = (m16 >> (chunk * 4 + 1)) & 1u;
        const bool f2 = (m16 >> (chunk * 4 + 2)) & 1u;
        const bool f3 = (m16 >> (chunk * 4 + 3)) & 1u;
        float4 me, mk;
        me.x = f0 ? mtv.x : ev.x;  mk.x = f0 ? 0.0f : 1.0f;
        me.y = f1 ? mtv.y : ev.y;  mk.y = f1 ? 0.0f : 1.0f;
        me.z = f2 ? mtv.z : ev.z;  mk.z = f2 ? 0.0f : 1.0f;
        me.w = f3 ? mtv.w : ev.w;  mk.w = f3 ? 0.0f : 1.0f;
        *(float4*)(out + base)        = me;
        *(float4*)(out + half + base) = mk;
    }
}

extern "C" void kernel_launch(void* const* d_in, const int* in_sizes, int n_in,
                              void* d_out, int out_size, void* d_ws, size_t ws_size,
                              hipStream_t stream) {
    const float* embeds     = (const float*)d_in[0];
    const float* factors    = (const float*)d_in[1];
    const float* mask_token = (const float*)d_in[2];
    float* out = (float*)d_out;
    (void)in_sizes; (void)n_in; (void)d_ws; (void)ws_size; (void)out_size;

    dim3 grid(B_ROWS / 4);   // 4 rows per block (one per wave)
    dim3 block(256);
    DynamicNodeMask_kernel<<<grid, block, 0, stream>>>(embeds, factors, mask_token, out);
}

// Round 6
// 370.449 us; speedup vs baseline: 1.0443x; 1.0059x over previous
//
#include <hip/hip_runtime.h>
#include <stdint.h>

// DynamicNodeMask — R6: R5 with nontemporal stores fixed (clang ext_vector_type
// instead of HIP_vector_type, which __builtin_nontemporal_store rejects).
// Structure: wave-per-row, entry prefetch of embeds/mask_token (overlaps the
// threefry VALU burst), wave-private LDS histogram + __shfl scan, register
// flag mask, nontemporal float4 output stores.
// RNG (verified exact, R3): partitionable Threefry-2x32, element n bits =
//   b1 ^ b2 of threefry2x32(key=(0,42), counts=(0, n)); score order == order
//   of (bits >> 9) with stable index tie-break.
// Per row: k = max(floor(307.2f*factor),1); mask k smallest, replace with
// mask_token. Outputs: [masked_embeds | mask], float32.

#define B_ROWS 32768
#define E_COLS 1024
#define MAXC 256   // boundary-bin candidate cap (binomial mean ~4)

typedef float vf4 __attribute__((ext_vector_type(4)));

__device__ __forceinline__ uint32_t rotl(uint32_t x, uint32_t d) {
    return (x << d) | (x >> (32u - d));
}

// JAX threefry2x32, key (0,42), counts (0, n); returns lane0 ^ lane1.
__device__ __forceinline__ uint32_t threefry_xor(uint32_t n) {
    const uint32_t ks0 = 0u;
    const uint32_t ks1 = 42u;
    const uint32_t ks2 = 0x1BD11BDAu ^ ks0 ^ ks1;
    uint32_t x0 = 0u;            // c0 (=0) + ks0 (=0)
    uint32_t x1 = n + ks1;
#define TF_ROUND(d) { x0 += x1; x1 = rotl(x1, d); x1 ^= x0; }
    TF_ROUND(13) TF_ROUND(15) TF_ROUND(26) TF_ROUND(6)
    x0 += ks1; x1 += ks2 + 1u;
    TF_ROUND(17) TF_ROUND(29) TF_ROUND(16) TF_ROUND(24)
    x0 += ks2; x1 += ks0 + 2u;
    TF_ROUND(13) TF_ROUND(15) TF_ROUND(26) TF_ROUND(6)
    x0 += ks0; x1 += ks1 + 3u;
    TF_ROUND(17) TF_ROUND(29) TF_ROUND(16) TF_ROUND(24)
    x0 += ks1; x1 += ks2 + 4u;
    TF_ROUND(13) TF_ROUND(15) TF_ROUND(26) TF_ROUND(6)
    x0 += ks2; x1 += ks0 + 5u;
#undef TF_ROUND
    return x0 ^ x1;
}

__global__ __launch_bounds__(256) void DynamicNodeMask_kernel(
    const float* __restrict__ embeds,        // [32768,1024]
    const float* __restrict__ factors,       // [32768]
    const float* __restrict__ mask_token,    // [1024]
    float* __restrict__ out)                 // [2*32768*1024]
{
    const int t    = threadIdx.x;
    const int w    = t >> 6;                 // wave 0..3
    const int lane = t & 63;
    const int r    = blockIdx.x * 4 + w;     // one row per wave

    __shared__ uint32_t s_hist[4][256];
    __shared__ uint32_t s_ckey[4][MAXC];
    __shared__ uint16_t s_cidx[4][MAXC];
    __shared__ uint32_t s_cnt[4];

    // ---- PREFETCH: issue the full read stream before the threefry burst ----
    const float f = factors[r];
    vf4 ev[4], mtv[4];
    const vf4* mt4 = (const vf4*)mask_token;
#pragma unroll
    for (int chunk = 0; chunk < 4; ++chunk) {
        const size_t base = (size_t)r * E_COLS + (size_t)chunk * 256 + (size_t)lane * 4;
        ev[chunk]  = *(const vf4*)(embeds + base);
        mtv[chunk] = mt4[chunk * 64 + lane];
    }

    // ---- 23-bit keys: element j = chunk*256 + lane*4 + e, slot s = chunk*4+e ----
    uint32_t u[16];
#pragma unroll
    for (int chunk = 0; chunk < 4; ++chunk)
#pragma unroll
        for (int e = 0; e < 4; ++e) {
            uint32_t j = (uint32_t)chunk * 256u + (uint32_t)lane * 4u + (uint32_t)e;
            u[chunk * 4 + e] = threefry_xor((uint32_t)r * 1024u + j) >> 9;
        }

    // ---- zero wave-private hist (stride-64: conflict-free) ----
#pragma unroll
    for (int i = 0; i < 4; ++i) s_hist[w][lane + 64 * i] = 0u;
    if (lane == 0) s_cnt[w] = 0u;
    __syncthreads();   // barrier 1

    // ---- histogram on top-8 bits ----
#pragma unroll
    for (int s = 0; s < 16; ++s)
        atomicAdd(&s_hist[w][u[s] >> 15], 1u);
    __syncthreads();   // barrier 2

    // ---- wave scan over 256 bins (lane owns bins 4*lane .. 4*lane+3) ----
    uint4 hv = *(const uint4*)&s_hist[w][lane * 4];
    const uint32_t s0 = hv.x, s1 = hv.y, s2 = hv.z, s3 = hv.w;
    const uint32_t L = s0 + s1 + s2 + s3;
    uint32_t scan = L;
#pragma unroll
    for (int d = 1; d < 64; d <<= 1) {
        uint32_t v = __shfl_up(scan, (unsigned)d, 64);
        scan += (lane >= d) ? v : 0u;
    }
    const uint32_t exclLane = scan - L;

    int ki = (int)floorf(307.2f * f);        // f32, matches JAX weak-type promotion
    if (ki < 1) ki = 1;
    const uint32_t k = (uint32_t)ki;

    // boundary bin: first bin whose inclusive count >= k
    const unsigned long long bal = __ballot(scan >= k);
    const int l0 = __ffsll(bal) - 1;         // first lane whose range crosses k
    const uint32_t i0 = exclLane + s0;
    const uint32_t i1 = i0 + s1;
    const uint32_t i2 = i1 + s2;
    const uint32_t i3 = i2 + s3;
    uint32_t b0loc, exloc;
    if      (i0 >= k) { b0loc = (uint32_t)lane * 4u + 0u; exloc = i0 - s0; }
    else if (i1 >= k) { b0loc = (uint32_t)lane * 4u + 1u; exloc = i1 - s1; }
    else if (i2 >= k) { b0loc = (uint32_t)lane * 4u + 2u; exloc = i2 - s2; }
    else              { b0loc = (uint32_t)lane * 4u + 3u; exloc = i3 - s3; }
    const uint32_t b0     = (uint32_t)__shfl((int)b0loc, l0, 64);
    const uint32_t excl   = (uint32_t)__shfl((int)exloc, l0, 64);
    const uint32_t kprime = k - excl;        // 1..|bin b0|

    // ---- flags in registers; gather boundary-bin candidates ----
    uint32_t m16 = 0u;
#pragma unroll
    for (int s = 0; s < 16; ++s) {
        const uint32_t bin = u[s] >> 15;
        if (bin < b0) m16 |= (1u << s);
        else if (bin == b0) {
            uint32_t pos = atomicAdd(&s_cnt[w], 1u);
            if (pos < MAXC) {
                uint32_t j = ((uint32_t)(s >> 2)) * 256u + (uint32_t)lane * 4u
                           + (uint32_t)(s & 3);
                s_ckey[w][pos] = u[s];
                s_cidx[w][pos] = (uint16_t)j;
            }
        }
    }
    __syncthreads();   // barrier 3

    // ---- exact stable rank among candidates (c ~ 4); all lanes redundantly ----
    uint32_t c = s_cnt[w];
    if (c > MAXC) c = MAXC;
    for (uint32_t p = 0; p < c; ++p) {
        const uint32_t up = s_ckey[w][p];    // broadcast reads: conflict-free
        const uint32_t jp = s_cidx[w][p];
        uint32_t rank = 0u;
        for (uint32_t q = 0; q < c; ++q) {
            const uint32_t uq = s_ckey[w][q];
            const uint32_t jq = s_cidx[w][q];
            rank += (uq < up || (uq == up && jq < jp)) ? 1u : 0u;
        }
        if (rank < kprime && (((jp >> 2) & 63u) == (uint32_t)lane))
            m16 |= 1u << ((jp >> 8) * 4u + (jp & 3u));
    }

    // ---- epilogue: select + nontemporal float4 stores (streams, no reuse) ----
    const size_t half = (size_t)B_ROWS * (size_t)E_COLS;
#pragma unroll
    for (int chunk = 0; chunk < 4; ++chunk) {
        const size_t base = (size_t)r * E_COLS + (size_t)chunk * 256 + (size_t)lane * 4;
        const bool f0 = (m16 >> (chunk * 4 + 0)) & 1u;
        const bool f1 = (m16 >> (chunk * 4 + 1)) & 1u;
        const bool f2 = (m16 >> (chunk * 4 + 2)) & 1u;
        const bool f3 = (m16 >> (chunk * 4 + 3)) & 1u;
        vf4 me, mk;
        me.x = f0 ? mtv[chunk].x : ev[chunk].x;  mk.x = f0 ? 0.0f : 1.0f;
        me.y = f1 ? mtv[chunk].y : ev[chunk].y;  mk.y = f1 ? 0.0f : 1.0f;
        me.z = f2 ? mtv[chunk].z : ev[chunk].z;  mk.z = f2 ? 0.0f : 1.0f;
        me.w = f3 ? mtv[chunk].w : ev[chunk].w;  mk.w = f3 ? 0.0f : 1.0f;
        __builtin_nontemporal_store(me, (vf4*)(out + base));
        __builtin_nontemporal_store(mk, (vf4*)(out + half + base));
    }
}

extern "C" void kernel_launch(void* const* d_in, const int* in_sizes, int n_in,
                              void* d_out, int out_size, void* d_ws, size_t ws_size,
                              hipStream_t stream) {
    const float* embeds     = (const float*)d_in[0];
    const float* factors    = (const float*)d_in[1];
    const float* mask_token = (const float*)d_in[2];
    float* out = (float*)d_out;
    (void)in_sizes; (void)n_in; (void)d_ws; (void)ws_size; (void)out_size;

    dim3 grid(B_ROWS / 4);   // 4 rows per block (one per wave)
    dim3 block(256);
    DynamicNodeMask_kernel<<<grid, block, 0, stream>>>(embeds, factors, mask_token, out);
}